// Round 4
// baseline (475.296 us; speedup 1.0000x reference)
//
#include <hip/hip_runtime.h>
#include <math.h>

// Rod_Block: N=8, C_IN=64, C_OUT=128, G=4, CG=16, K=3, P=9, PAD=1, H=W=64.
// All tensors fp32 (reference is jnp.float32 end-to-end). Padded spatial 66x66.

// ---- K0b: zero padded proj buffer (2,230,272 floats = 8712*256) ----
__global__ void k_zero(float* p) {
    p[(size_t)blockIdx.x * 256 + threadIdx.x] = 0.f;
}

// ---- K1: pooled[n,c] = mean_{h,w} x[n,c,h,w]  (512 blocks x 256) ----
__global__ void k_pool(const float* x, float* pooled) {
    __shared__ float red[256];
    int nc = blockIdx.x;
    const float* p = x + (size_t)nc * 4096;
    float s = 0.f;
    for (int i = threadIdx.x; i < 4096; i += 256) s += p[i];
    red[threadIdx.x] = s;
    __syncthreads();
    for (int o = 128; o > 0; o >>= 1) {
        if (threadIdx.x < o) red[threadIdx.x] += red[threadIdx.x + o];
        __syncthreads();
    }
    if (threadIdx.x == 0) pooled[nc] = red[0] * (1.f / 4096.f);
}

// ---- K2: gain1p = 1 + sigmoid(relu(pooled@gw1+gb1)@gw2+gb2)  (1 block x 256) ----
__global__ void k_gain(const float* pooled,
                       const float* gw1, const float* gb1,
                       const float* gw2, const float* gb2,
                       float* gain1p) {
    __shared__ float hid[128];
    int tid = threadIdx.x;
    if (tid < 128) {
        int n = tid >> 4, j = tid & 15;
        float s = gb1[j];
        for (int c = 0; c < 64; ++c) s += pooled[n * 64 + c] * gw1[c * 16 + j];
        hid[tid] = fmaxf(s, 0.f);
    }
    __syncthreads();
    for (int t = tid; t < 512; t += 256) {
        int n = t >> 6, c = t & 63;
        float s = gb2[c];
        for (int j = 0; j < 16; ++j) s += hid[n * 16 + j] * gw2[j * 64 + c];
        gain1p[t] = 1.f + 1.f / (1.f + expf(-s));
    }
}

// ---- K3: xs(NHWC) = x*(1+gain) + relu(refl*tap_w+tap_b)  (512 blocks x 256) ----
__global__ void k_xs(const float* x, const float* refl,
                     const float* tap_w, const float* tap_b,
                     const float* gain1p, float* xs) {
    __shared__ float tile[64 * 65];
    __shared__ float rrow[64];
    int n = blockIdx.x >> 6, h = blockIdx.x & 63;
    int tid = threadIdx.x;
    for (int i = tid; i < 4096; i += 256) {
        int c = i >> 6, w = i & 63;
        tile[c * 65 + w] = x[(((size_t)(n * 64 + c)) * 64 + h) * 64 + w];
    }
    if (tid < 64) rrow[tid] = refl[n * 4096 + h * 64 + tid];
    __syncthreads();
    for (int i = tid; i < 4096; i += 256) {
        int w = i >> 6, c = i & 63;
        float r = fmaxf(rrow[w] * tap_w[c] + tap_b[c], 0.f);
        xs[(((size_t)(n * 64 + h)) * 64 + w) * 64 + c] =
            tile[c * 65 + w] * gain1p[n * 64 + c] + r;
    }
}

// ---- K4: input_proj into padded buffer interior  (32768 blocks x 64) ----
__global__ void k_proj(const float* xs, const float* inp_w,
                       const float* inp_b, float* xpad) {
    __shared__ float xr[64];
    int pix = blockIdx.x;
    int co = threadIdx.x;
    xr[co] = xs[(size_t)pix * 64 + co];
    __syncthreads();
    float s = inp_b[co];
    for (int c = 0; c < 64; ++c) s += xr[c] * inp_w[c * 64 + co];
    int n = pix >> 12, h = (pix >> 6) & 63, w = pix & 63;
    xpad[((((size_t)n * 66) + (h + 1)) * 66 + (w + 1)) * 64 + co] = s;
}

// ---- K5: depthwise 3x3 + LayerNorm + exact GELU  (32768 blocks x 64) ----
__global__ void k_dw(const float* xs,
                     const float* dw_w, const float* dw_b,
                     const float* ln_g, const float* ln_b,
                     float* dwo) {
    __shared__ float red[64];
    __shared__ float red2[64];
    int pix = blockIdx.x;
    int lane = threadIdx.x;
    int n = pix >> 12, h = (pix >> 6) & 63, w = pix & 63;
    float s = dw_b[lane];
    for (int ky = 0; ky < 3; ++ky) {
        int y = h + ky - 1;
        if (y < 0 || y > 63) continue;
        for (int kx = 0; kx < 3; ++kx) {
            int x2 = w + kx - 1;
            if (x2 < 0 || x2 > 63) continue;
            s += xs[(((size_t)(n * 64 + y)) * 64 + x2) * 64 + lane]
                 * dw_w[(ky * 3 + kx) * 64 + lane];
        }
    }
    red[lane] = s;
    red2[lane] = s * s;
    __syncthreads();
    for (int o = 32; o > 0; o >>= 1) {
        if (lane < o) { red[lane] += red[lane + o]; red2[lane] += red2[lane + o]; }
        __syncthreads();
    }
    float mu = red[0] * (1.f / 64.f);
    float var = red2[0] * (1.f / 64.f) - mu * mu;
    float nrm = (s - mu) * rsqrtf(var + 1e-6f) * ln_g[lane] + ln_b[lane];
    float ge = 0.5f * nrm * (1.f + erff(nrm * 0.70710678118654752f));
    dwo[(size_t)pix * 64 + lane] = ge;
}

// ---- K6: offset/mask proj -> softmax -> bilinear -> output_proj -> BN1 -> ReLU ----
// (32768 blocks x 64; one block = one pixel)
__global__ void k_samp(const float* dwo, const float* xpad,
                       const float* off_w, const float* off_b,
                       const float* mask_w, const float* mask_b,
                       const float* outp_w, const float* outp_b,
                       const float* bn1_g, const float* bn1_b,
                       const float* bn1_m, const float* bn1_v,
                       float* vbuf) {
    __shared__ float dwr[64];
    __shared__ float om[112];   // [0..71] offsets, [72..107] mask
    __shared__ float dcnl[64];
    int pix = blockIdx.x;
    int lane = threadIdx.x;
    int n = pix >> 12, h = (pix >> 6) & 63, w = pix & 63;
    dwr[lane] = dwo[(size_t)pix * 64 + lane];
    __syncthreads();

    // 108 length-64 dots: lane handles j=lane, plus j=lane+64 for lane<44
    {
        int j2 = lane + 64;
        int has2 = (lane < 44) ? 1 : 0;
        float a1 = off_b[lane];
        float a2 = 0.f;
        if (has2) a2 = (j2 < 72) ? off_b[j2] : mask_b[j2 - 72];
        for (int c = 0; c < 64; ++c) {
            float d = dwr[c];
            a1 += d * off_w[c * 72 + lane];
            if (has2) {
                float wv = (j2 < 72) ? off_w[c * 72 + j2]
                                     : mask_w[c * 36 + (j2 - 72)];
                a2 += d * wv;
            }
        }
        om[lane] = a1;
        if (has2) om[j2] = a2;
    }
    __syncthreads();

    // softmax over P=9 per group (lanes 0..3)
    if (lane < 4) {
        float m = -1e30f;
        for (int p = 0; p < 9; ++p) m = fmaxf(m, om[72 + lane * 9 + p]);
        float ssum = 0.f;
        float e[9];
        for (int p = 0; p < 9; ++p) { e[p] = expf(om[72 + lane * 9 + p] - m); ssum += e[p]; }
        float inv = 1.f / ssum;
        for (int p = 0; p < 9; ++p) om[72 + lane * 9 + p] = e[p] * inv;
    }
    __syncthreads();

    // bilinear sampling (zeros padding); lane = channel, group g = lane>>4
    {
        int g = lane >> 4;
        const float* xpn = xpad + (size_t)n * 66 * 66 * 64;
        float acc = 0.f;
        for (int p = 0; p < 9; ++p) {
            float ox = om[g * 18 + p * 2];
            float oy = om[g * 18 + p * 2 + 1];
            float mk = om[72 + g * 9 + p];
            // kernel grid: w-outer (p/3), h-inner (p%3)
            float px = (float)(w + (p / 3)) + ox;
            float py = (float)(h + (p % 3)) + oy;
            float x0f = floorf(px), y0f = floorf(py);
            float wx = px - x0f, wy = py - y0f;
            int x0 = (int)x0f, y0 = (int)y0f;
            float v00 = 0.f, v01 = 0.f, v10 = 0.f, v11 = 0.f;
            int yok0 = (y0 >= 0) && (y0 < 66);
            int yok1 = (y0 + 1 >= 0) && (y0 + 1 < 66);
            int xok0 = (x0 >= 0) && (x0 < 66);
            int xok1 = (x0 + 1 >= 0) && (x0 + 1 < 66);
            if (yok0 && xok0) v00 = xpn[((size_t)y0 * 66 + x0) * 64 + lane];
            if (yok0 && xok1) v01 = xpn[((size_t)y0 * 66 + x0 + 1) * 64 + lane];
            if (yok1 && xok0) v10 = xpn[((size_t)(y0 + 1) * 66 + x0) * 64 + lane];
            if (yok1 && xok1) v11 = xpn[((size_t)(y0 + 1) * 66 + x0 + 1) * 64 + lane];
            float bl = v00 * (1.f - wy) * (1.f - wx) + v01 * (1.f - wy) * wx
                     + v10 * wy * (1.f - wx) + v11 * wy * wx;
            acc += mk * bl;
        }
        dcnl[lane] = acc;
    }
    __syncthreads();

    // output_proj + BN1(eval) + ReLU
    {
        float s = outp_b[lane];
        for (int c = 0; c < 64; ++c) s += dcnl[c] * outp_w[c * 64 + lane];
        float sc = bn1_g[lane] * rsqrtf(bn1_v[lane] + 1e-5f);
        float v = sc * (s - bn1_m[lane]) + bn1_b[lane];
        vbuf[(size_t)pix * 64 + lane] = fmaxf(v, 0.f);
    }
}

// ---- K7: 1x1 conv 64->128 + BN2 + ReLU, fp32 NCHW out  (512 blocks x 256) ----
__global__ void k_out(const float* vbuf,
                      const float* conv_w, const float* conv_b,
                      const float* bn2_g, const float* bn2_b,
                      const float* bn2_m, const float* bn2_v,
                      float* out) {
    __shared__ float vl[64 * 65];   // [w][c], pad 65
    int n = blockIdx.x >> 6, h = blockIdx.x & 63;
    int tid = threadIdx.x;
    const float* vrow = vbuf + ((size_t)(n * 64 + h)) * 4096;
    for (int i = tid; i < 4096; i += 256) {
        int w = i >> 6, c = i & 63;
        vl[w * 65 + c] = vrow[i];
    }
    __syncthreads();
    int w = tid & 63;
    int dg = tid >> 6;              // 0..3
    for (int j = 0; j < 32; ++j) {
        int d = dg * 32 + j;
        float acc = conv_b[d];
        for (int c = 0; c < 64; ++c)
            acc += vl[w * 65 + c] * conv_w[c * 128 + d];
        float sc = bn2_g[d] * rsqrtf(bn2_v[d] + 1e-5f);
        float y = sc * (acc - bn2_m[d]) + bn2_b[d];
        out[(((size_t)(n * 128 + d)) * 64 + h) * 64 + w] = fmaxf(y, 0.f);
    }
}

extern "C" void kernel_launch(void* const* d_in, const int* in_sizes, int n_in,
                              void* d_out, int out_size, void* d_ws, size_t ws_size,
                              hipStream_t stream) {
    const float* x      = (const float*)d_in[0];
    const float* refl   = (const float*)d_in[1];
    const float* gw1    = (const float*)d_in[2];
    const float* gb1    = (const float*)d_in[3];
    const float* gw2    = (const float*)d_in[4];
    const float* gb2    = (const float*)d_in[5];
    const float* tap_w  = (const float*)d_in[6];
    const float* tap_b  = (const float*)d_in[7];
    const float* dw_w   = (const float*)d_in[8];
    const float* dw_b   = (const float*)d_in[9];
    const float* ln_g   = (const float*)d_in[10];
    const float* ln_b   = (const float*)d_in[11];
    const float* inp_w  = (const float*)d_in[12];
    const float* inp_b  = (const float*)d_in[13];
    const float* off_w  = (const float*)d_in[14];
    const float* off_b  = (const float*)d_in[15];
    const float* mask_w = (const float*)d_in[16];
    const float* mask_b = (const float*)d_in[17];
    const float* outp_w = (const float*)d_in[18];
    const float* outp_b = (const float*)d_in[19];
    const float* conv_w = (const float*)d_in[20];
    const float* conv_b = (const float*)d_in[21];
    const float* bn1_g  = (const float*)d_in[22];
    const float* bn1_b  = (const float*)d_in[23];
    const float* bn1_m  = (const float*)d_in[24];
    const float* bn1_v  = (const float*)d_in[25];
    const float* bn2_g  = (const float*)d_in[26];
    const float* bn2_b  = (const float*)d_in[27];
    const float* bn2_m  = (const float*)d_in[28];
    const float* bn2_v  = (const float*)d_in[29];

    // workspace (floats), vbuf aliases xs (xs dead after k_dw): ~24.5 MiB total
    float* ws     = (float*)d_ws;
    float* pooled = ws;                    // 512
    float* gain1p = ws + 512;              // 512
    float* xs     = ws + 1024;             // 2,097,152  (NHWC)
    float* xpad   = xs + 2097152;          // 2,230,272  (8*66*66*64, NHWC padded)
    float* dwo    = xpad + 2230272;        // 2,097,152
    float* vbuf   = xs;                    // alias

    k_zero<<<8712, 256, 0, stream>>>(xpad);
    k_pool<<<512, 256, 0, stream>>>(x, pooled);
    k_gain<<<1, 256, 0, stream>>>(pooled, gw1, gb1, gw2, gb2, gain1p);
    k_xs<<<512, 256, 0, stream>>>(x, refl, tap_w, tap_b, gain1p, xs);
    k_dw<<<32768, 64, 0, stream>>>(xs, dw_w, dw_b, ln_g, ln_b, dwo);
    k_proj<<<32768, 64, 0, stream>>>(xs, inp_w, inp_b, xpad);
    k_samp<<<32768, 64, 0, stream>>>(dwo, xpad, off_w, off_b, mask_w, mask_b,
                                     outp_w, outp_b, bn1_g, bn1_b, bn1_m, bn1_v, vbuf);
    k_out<<<512, 256, 0, stream>>>(vbuf, conv_w, conv_b, bn2_g, bn2_b, bn2_m, bn2_v,
                                   (float*)d_out);
}

// Round 5
// 307.081 us; speedup vs baseline: 1.5478x; 1.5478x over previous
//
#include <hip/hip_runtime.h>
#include <math.h>

// Rod_Block: N=8, C_IN=64, C_OUT=128, G=4, CG=16, K=3, P=9, PAD=1, H=W=64.
// All tensors fp32. Padded spatial 66x66. Round-5: k_out LDS+regtile rewrite,
// k_dw fused into k_samp, 4-pixel batching, float4 loads.

// ---- K0: zero padded proj buffer (2,230,272 floats = 557,568 float4 = 2178*256) ----
__global__ __launch_bounds__(256) void k_zero(float4* p) {
    p[(size_t)blockIdx.x * 256 + threadIdx.x] = make_float4(0.f, 0.f, 0.f, 0.f);
}

// ---- K1: pooled[n,c] = mean_{h,w} x[n,c,h,w]  (512 blocks x 256) ----
__global__ __launch_bounds__(256) void k_pool(const float* x, float* pooled) {
    __shared__ float red[256];
    int nc = blockIdx.x;
    const float4* p4 = reinterpret_cast<const float4*>(x + (size_t)nc * 4096);
    float s = 0.f;
    for (int i = threadIdx.x; i < 1024; i += 256) {
        float4 v = p4[i];
        s += v.x + v.y + v.z + v.w;
    }
    red[threadIdx.x] = s;
    __syncthreads();
    for (int o = 128; o > 0; o >>= 1) {
        if (threadIdx.x < o) red[threadIdx.x] += red[threadIdx.x + o];
        __syncthreads();
    }
    if (threadIdx.x == 0) pooled[nc] = red[0] * (1.f / 4096.f);
}

// ---- K2: gain1p = 1 + sigmoid(relu(pooled@gw1+gb1)@gw2+gb2)  (1 block x 256) ----
__global__ __launch_bounds__(256) void k_gain(const float* pooled,
                       const float* gw1, const float* gb1,
                       const float* gw2, const float* gb2,
                       float* gain1p) {
    __shared__ float hid[128];
    int tid = threadIdx.x;
    if (tid < 128) {
        int n = tid >> 4, j = tid & 15;
        float s = gb1[j];
        for (int c = 0; c < 64; ++c) s += pooled[n * 64 + c] * gw1[c * 16 + j];
        hid[tid] = fmaxf(s, 0.f);
    }
    __syncthreads();
    for (int t = tid; t < 512; t += 256) {
        int n = t >> 6, c = t & 63;
        float s = gb2[c];
        for (int j = 0; j < 16; ++j) s += hid[n * 16 + j] * gw2[j * 64 + c];
        gain1p[t] = 1.f + 1.f / (1.f + expf(-s));
    }
}

// ---- K3: xs(NHWC) = x*(1+gain) + relu(refl*tap_w+tap_b)  (512 blocks x 256) ----
__global__ __launch_bounds__(256) void k_xs(const float* x, const float* refl,
                     const float* tap_w, const float* tap_b,
                     const float* gain1p, float* xs) {
    __shared__ float tile[64 * 65];
    __shared__ float rrow[64];
    int n = blockIdx.x >> 6, h = blockIdx.x & 63;
    int tid = threadIdx.x;
    for (int i = tid; i < 4096; i += 256) {
        int c = i >> 6, w = i & 63;
        tile[c * 65 + w] = x[(((size_t)(n * 64 + c)) * 64 + h) * 64 + w];
    }
    if (tid < 64) rrow[tid] = refl[n * 4096 + h * 64 + tid];
    __syncthreads();
    for (int i = tid; i < 4096; i += 256) {
        int w = i >> 6, c = i & 63;
        float r = fmaxf(rrow[w] * tap_w[c] + tap_b[c], 0.f);
        xs[(((size_t)(n * 64 + h)) * 64 + w) * 64 + c] =
            tile[c * 65 + w] * gain1p[n * 64 + c] + r;
    }
}

// ---- K4: input_proj into padded buffer interior (8192 blocks x 256, 4 pix/block) ----
__global__ __launch_bounds__(256) void k_proj(const float* xs, const float* inp_w,
                       const float* inp_b, float* xpad) {
    __shared__ float wl[64 * 64];
    __shared__ float xr[4][64];
    int tid = threadIdx.x;
    for (int i = tid; i < 1024; i += 256)
        *reinterpret_cast<float4*>(&wl[i * 4]) = reinterpret_cast<const float4*>(inp_w)[i];
    int p = tid >> 6, co = tid & 63;
    int pix = blockIdx.x * 4 + p;
    xr[p][co] = xs[(size_t)pix * 64 + co];
    __syncthreads();
    float s = inp_b[co];
    for (int c = 0; c < 64; ++c) s += xr[p][c] * wl[c * 64 + co];
    int n = pix >> 12, h = (pix >> 6) & 63, w = pix & 63;
    xpad[((((size_t)n * 66) + (h + 1)) * 66 + (w + 1)) * 64 + co] = s;
}

// ---- K5 (fused dw+LN+GELU + offset/mask + softmax + bilinear + outproj + BN1) ----
// 8192 blocks x 256; wave wv handles pixel blockIdx.x*4+wv, lane = channel.
__global__ __launch_bounds__(256) void k_dwsamp(const float* xs, const float* xpad,
                       const float* dw_w, const float* dw_b,
                       const float* ln_g, const float* ln_b,
                       const float* off_w, const float* off_b,
                       const float* mask_w, const float* mask_b,
                       const float* outp_w, const float* outp_b,
                       const float* bn1_g, const float* bn1_b,
                       const float* bn1_m, const float* bn1_v,
                       float* vbuf) {
    __shared__ float dwr[4][64];
    __shared__ float om[4][112];   // [0..71] offsets, [72..107] mask
    __shared__ float dcnl[4][64];
    int lane = threadIdx.x & 63, wv = threadIdx.x >> 6;
    int pix = blockIdx.x * 4 + wv;
    int n = pix >> 12, h = (pix >> 6) & 63, w = pix & 63;

    // depthwise 3x3 ('SAME', zero pad) on xs
    float s = dw_b[lane];
    for (int ky = 0; ky < 3; ++ky) {
        int y = h + ky - 1;
        if (y < 0 || y > 63) continue;
        for (int kx = 0; kx < 3; ++kx) {
            int x2 = w + kx - 1;
            if (x2 < 0 || x2 > 63) continue;
            s += xs[(((size_t)(n * 64 + y)) * 64 + x2) * 64 + lane]
                 * dw_w[(ky * 3 + kx) * 64 + lane];
        }
    }
    // LayerNorm over 64 channels via wave shuffle + exact GELU
    float sum = s, sq = s * s;
    for (int o = 32; o > 0; o >>= 1) {
        sum += __shfl_xor(sum, o, 64);
        sq  += __shfl_xor(sq,  o, 64);
    }
    float mu = sum * (1.f / 64.f);
    float var = sq * (1.f / 64.f) - mu * mu;
    float nrm = (s - mu) * rsqrtf(var + 1e-6f) * ln_g[lane] + ln_b[lane];
    float ge = 0.5f * nrm * (1.f + erff(nrm * 0.70710678118654752f));
    dwr[wv][lane] = ge;
    __syncthreads();

    // 108 length-64 dots: lane handles j=lane, plus j=lane+64 for lane<44
    {
        int j2 = lane + 64;
        int has2 = (lane < 44) ? 1 : 0;
        float a1 = off_b[lane];
        float a2 = 0.f;
        if (has2) a2 = (j2 < 72) ? off_b[j2] : mask_b[j2 - 72];
        for (int c = 0; c < 64; ++c) {
            float d = dwr[wv][c];
            a1 += d * off_w[c * 72 + lane];
            if (has2) {
                float wt = (j2 < 72) ? off_w[c * 72 + j2]
                                     : mask_w[c * 36 + (j2 - 72)];
                a2 += d * wt;
            }
        }
        om[wv][lane] = a1;
        if (has2) om[wv][j2] = a2;
    }
    __syncthreads();

    // softmax over P=9 per group (lanes 0..3)
    if (lane < 4) {
        float m = -1e30f;
        for (int p = 0; p < 9; ++p) m = fmaxf(m, om[wv][72 + lane * 9 + p]);
        float ssum = 0.f;
        float e[9];
        for (int p = 0; p < 9; ++p) { e[p] = expf(om[wv][72 + lane * 9 + p] - m); ssum += e[p]; }
        float inv = 1.f / ssum;
        for (int p = 0; p < 9; ++p) om[wv][72 + lane * 9 + p] = e[p] * inv;
    }
    __syncthreads();

    // bilinear sampling (zeros padding); lane = channel, group g = lane>>4
    {
        int g = lane >> 4;
        const float* xpn = xpad + (size_t)n * 66 * 66 * 64;
        float acc = 0.f;
        for (int p = 0; p < 9; ++p) {
            float ox = om[wv][g * 18 + p * 2];
            float oy = om[wv][g * 18 + p * 2 + 1];
            float mk = om[wv][72 + g * 9 + p];
            // kernel grid: w-outer (p/3), h-inner (p%3)
            float px = (float)(w + (p / 3)) + ox;
            float py = (float)(h + (p % 3)) + oy;
            float x0f = floorf(px), y0f = floorf(py);
            float wx = px - x0f, wy = py - y0f;
            int x0 = (int)x0f, y0 = (int)y0f;
            float v00 = 0.f, v01 = 0.f, v10 = 0.f, v11 = 0.f;
            int yok0 = (y0 >= 0) && (y0 < 66);
            int yok1 = (y0 + 1 >= 0) && (y0 + 1 < 66);
            int xok0 = (x0 >= 0) && (x0 < 66);
            int xok1 = (x0 + 1 >= 0) && (x0 + 1 < 66);
            if (yok0 && xok0) v00 = xpn[((size_t)y0 * 66 + x0) * 64 + lane];
            if (yok0 && xok1) v01 = xpn[((size_t)y0 * 66 + x0 + 1) * 64 + lane];
            if (yok1 && xok0) v10 = xpn[((size_t)(y0 + 1) * 66 + x0) * 64 + lane];
            if (yok1 && xok1) v11 = xpn[((size_t)(y0 + 1) * 66 + x0 + 1) * 64 + lane];
            float bl = v00 * (1.f - wy) * (1.f - wx) + v01 * (1.f - wy) * wx
                     + v10 * wy * (1.f - wx) + v11 * wy * wx;
            acc += mk * bl;
        }
        dcnl[wv][lane] = acc;
    }
    __syncthreads();

    // output_proj + BN1(eval) + ReLU
    {
        float s2 = outp_b[lane];
        for (int c = 0; c < 64; ++c) s2 += dcnl[wv][c] * outp_w[c * 64 + lane];
        float sc = bn1_g[lane] * rsqrtf(bn1_v[lane] + 1e-5f);
        float v = sc * (s2 - bn1_m[lane]) + bn1_b[lane];
        vbuf[(size_t)pix * 64 + lane] = fmaxf(v, 0.f);
    }
}

// ---- K6: 1x1 conv 64->128 + BN2 + ReLU, fp32 NCHW out (512 blocks x 256) ----
__global__ __launch_bounds__(256) void k_out(const float* vbuf,
                      const float* conv_w, const float* conv_b,
                      const float* bn2_g, const float* bn2_b,
                      const float* bn2_m, const float* bn2_v,
                      float* out) {
    __shared__ float vl[64 * 68];    // [w][c], pad 68 (272 B rows, 16B-aligned)
    __shared__ float cwl[64 * 128];  // [c][d]
    int n = blockIdx.x >> 6, h = blockIdx.x & 63;
    int tid = threadIdx.x;
    const float4* vrow4 = reinterpret_cast<const float4*>(vbuf + ((size_t)(n * 64 + h)) * 4096);
    for (int i = tid; i < 1024; i += 256) {
        int idx = i * 4;
        int w = idx >> 6, c = idx & 63;
        *reinterpret_cast<float4*>(&vl[w * 68 + c]) = vrow4[i];
    }
    for (int i = tid; i < 2048; i += 256)
        *reinterpret_cast<float4*>(&cwl[i * 4]) = reinterpret_cast<const float4*>(conv_w)[i];
    __syncthreads();

    int dgrp = tid & 15, wgrp = tid >> 4;   // thread tile: 4 w x 8 d
    int dbase = dgrp * 8, wbase = wgrp * 4;
    float acc[4][8];
    #pragma unroll
    for (int i = 0; i < 4; ++i)
        #pragma unroll
        for (int j = 0; j < 8; ++j) acc[i][j] = 0.f;

    for (int c = 0; c < 64; ++c) {
        float v0 = vl[(wbase + 0) * 68 + c];
        float v1 = vl[(wbase + 1) * 68 + c];
        float v2 = vl[(wbase + 2) * 68 + c];
        float v3 = vl[(wbase + 3) * 68 + c];
        const float4* c4 = reinterpret_cast<const float4*>(&cwl[c * 128 + dbase]);
        float4 wA = c4[0], wB = c4[1];
        float wt[8] = {wA.x, wA.y, wA.z, wA.w, wB.x, wB.y, wB.z, wB.w};
        #pragma unroll
        for (int j = 0; j < 8; ++j) {
            acc[0][j] += v0 * wt[j];
            acc[1][j] += v1 * wt[j];
            acc[2][j] += v2 * wt[j];
            acc[3][j] += v3 * wt[j];
        }
    }

    #pragma unroll
    for (int j = 0; j < 8; ++j) {
        int d = dbase + j;
        float sc = bn2_g[d] * rsqrtf(bn2_v[d] + 1e-5f);
        float sh = sc * (conv_b[d] - bn2_m[d]) + bn2_b[d];
        float4 r;
        r.x = fmaxf(sc * acc[0][j] + sh, 0.f);
        r.y = fmaxf(sc * acc[1][j] + sh, 0.f);
        r.z = fmaxf(sc * acc[2][j] + sh, 0.f);
        r.w = fmaxf(sc * acc[3][j] + sh, 0.f);
        size_t o = (((size_t)(n * 128 + d)) * 64 + h) * 64 + wbase;
        *reinterpret_cast<float4*>(out + o) = r;
    }
}

extern "C" void kernel_launch(void* const* d_in, const int* in_sizes, int n_in,
                              void* d_out, int out_size, void* d_ws, size_t ws_size,
                              hipStream_t stream) {
    const float* x      = (const float*)d_in[0];
    const float* refl   = (const float*)d_in[1];
    const float* gw1    = (const float*)d_in[2];
    const float* gb1    = (const float*)d_in[3];
    const float* gw2    = (const float*)d_in[4];
    const float* gb2    = (const float*)d_in[5];
    const float* tap_w  = (const float*)d_in[6];
    const float* tap_b  = (const float*)d_in[7];
    const float* dw_w   = (const float*)d_in[8];
    const float* dw_b   = (const float*)d_in[9];
    const float* ln_g   = (const float*)d_in[10];
    const float* ln_b   = (const float*)d_in[11];
    const float* inp_w  = (const float*)d_in[12];
    const float* inp_b  = (const float*)d_in[13];
    const float* off_w  = (const float*)d_in[14];
    const float* off_b  = (const float*)d_in[15];
    const float* mask_w = (const float*)d_in[16];
    const float* mask_b = (const float*)d_in[17];
    const float* outp_w = (const float*)d_in[18];
    const float* outp_b = (const float*)d_in[19];
    const float* conv_w = (const float*)d_in[20];
    const float* conv_b = (const float*)d_in[21];
    const float* bn1_g  = (const float*)d_in[22];
    const float* bn1_b  = (const float*)d_in[23];
    const float* bn1_m  = (const float*)d_in[24];
    const float* bn1_v  = (const float*)d_in[25];
    const float* bn2_g  = (const float*)d_in[26];
    const float* bn2_b  = (const float*)d_in[27];
    const float* bn2_m  = (const float*)d_in[28];
    const float* bn2_v  = (const float*)d_in[29];

    // workspace (floats): 512+512+2,097,152+2,230,272+2,097,152 = 6,425,600 (~25.7 MiB)
    float* ws     = (float*)d_ws;
    float* pooled = ws;                    // 512
    float* gain1p = ws + 512;              // 512
    float* xs     = ws + 1024;             // 2,097,152  (NHWC)
    float* xpad   = xs + 2097152;          // 2,230,272  (8*66*66*64, NHWC padded)
    float* vbuf   = xpad + 2230272;        // 2,097,152  (post BN1+ReLU, NHWC)

    k_zero<<<2178, 256, 0, stream>>>((float4*)xpad);
    k_pool<<<512, 256, 0, stream>>>(x, pooled);
    k_gain<<<1, 256, 0, stream>>>(pooled, gw1, gb1, gw2, gb2, gain1p);
    k_xs<<<512, 256, 0, stream>>>(x, refl, tap_w, tap_b, gain1p, xs);
    k_proj<<<8192, 256, 0, stream>>>(xs, inp_w, inp_b, xpad);
    k_dwsamp<<<8192, 256, 0, stream>>>(xs, xpad, dw_w, dw_b, ln_g, ln_b,
                                       off_w, off_b, mask_w, mask_b,
                                       outp_w, outp_b, bn1_g, bn1_b, bn1_m, bn1_v, vbuf);
    k_out<<<512, 256, 0, stream>>>(vbuf, conv_w, conv_b, bn2_g, bn2_b, bn2_m, bn2_v,
                                   (float*)d_out);
}